// Round 1
// baseline (1374.242 us; speedup 1.0000x reference)
//
#include <hip/hip_runtime.h>

// ParallelTransport: out[b,i,j,:,:] = exp6(M) where M = Tjrow - T_i,
//   T[i,m] = sum_d x[b,i,d] * A[b,j,d,m]   (m = k*8+l, K=8)
// One block per (b,j). fp32 baseline (compute-bound ~478us floor on vector ALU).

constexpr int S  = 512;
constexpr int D  = 512;
constexpr int MM = 64;      // K*K = 8*8
constexpr int TILE_I = 128; // i-rows per tile (4 tiles)
constexpr int DK = 32;      // d-chunk
constexpr int XS_STRIDE = 132;  // pad 128 -> 132 (16B-aligned rows, conflict-free)
constexpr int TS_STRIDE = 65;   // pad 64 -> 65 (conflict-free column reads)

__global__ __launch_bounds__(256, 2)
void pt_kernel(const float* __restrict__ x, const float* __restrict__ A,
               float* __restrict__ out, int B) {
  const int b = blockIdx.x >> 9;        // / S
  const int j = blockIdx.x & (S - 1);
  const int t = threadIdx.x;

  __shared__ float Xs[DK][XS_STRIDE];   // [dd][ii] transposed X tile
  __shared__ float As[DK][MM];          // [dd][m]
  __shared__ float Ts[TILE_I][TS_STRIDE];
  __shared__ float Tjrow[MM];
  __shared__ float red[4][MM];

  const float* xb = x + (size_t)b * S * D;
  const float* Ab = A + (size_t)(b * S + j) * ((size_t)D * MM);

  // ---- pre-pass: Tjrow[m] = sum_d x[b,j,d] * A[b,j,d,m] (also warms L2 with A[b,j]) ----
  {
    const int m = t & 63;
    const int part = t >> 6;            // 0..3, each covers 128 d's
    const float* xj = xb + (size_t)j * D;
    const int dbeg = part * (D / 4);
    float acc = 0.f;
    for (int dd = 0; dd < D / 4; ++dd) {
      acc += xj[dbeg + dd] * Ab[(size_t)(dbeg + dd) * MM + m];
    }
    red[part][m] = acc;
  }
  __syncthreads();
  if (t < MM) Tjrow[t] = red[0][t] + red[1][t] + red[2][t] + red[3][t];
  // (visibility guaranteed by the barrier at the top of the d0 loop below)

  const int ty = t >> 4;   // 0..15 -> rows ty*8 .. ty*8+7
  const int tx = t & 15;   // 0..15 -> cols tx*4 .. tx*4+3

  for (int tile = 0; tile < S / TILE_I; ++tile) {
    const int i0 = tile * TILE_I;

    float acc[8][4];
#pragma unroll
    for (int r = 0; r < 8; ++r)
#pragma unroll
      for (int c = 0; c < 4; ++c) acc[r][c] = 0.f;

    for (int d0 = 0; d0 < D; d0 += DK) {
      __syncthreads();  // protect LDS from readers of previous chunk / epilogue
      // stage X tile: 128 rows x 32 d, as float4, transposed into Xs[dd][ii]
#pragma unroll
      for (int rep = 0; rep < 4; ++rep) {
        const int idx = rep * 256 + t;      // 0..1023
        const int ii = idx >> 3;            // 0..127
        const int dq = idx & 7;             // float4 column
        const float4 v = *(const float4*)(xb + (size_t)(i0 + ii) * D + d0 + dq * 4);
        Xs[dq * 4 + 0][ii] = v.x;
        Xs[dq * 4 + 1][ii] = v.y;
        Xs[dq * 4 + 2][ii] = v.z;
        Xs[dq * 4 + 3][ii] = v.w;
      }
      // stage A tile: 32 d x 64 m
#pragma unroll
      for (int rep = 0; rep < 2; ++rep) {
        const int idx = rep * 256 + t;      // 0..511
        const int dd = idx >> 4;
        const int m4 = idx & 15;
        const float4 v = *(const float4*)(Ab + (size_t)(d0 + dd) * MM + m4 * 4);
        *(float4*)&As[dd][m4 * 4] = v;
      }
      __syncthreads();

#pragma unroll 8
      for (int dd = 0; dd < DK; ++dd) {
        const float4 av = *(const float4*)&As[dd][tx * 4];
        const float4 xv0 = *(const float4*)&Xs[dd][ty * 8];
        const float4 xv1 = *(const float4*)&Xs[dd][ty * 8 + 4];
        const float xr[8] = {xv0.x, xv0.y, xv0.z, xv0.w, xv1.x, xv1.y, xv1.z, xv1.w};
#pragma unroll
        for (int r = 0; r < 8; ++r) {
          acc[r][0] += xr[r] * av.x;
          acc[r][1] += xr[r] * av.y;
          acc[r][2] += xr[r] * av.z;
          acc[r][3] += xr[r] * av.w;
        }
      }
    }

    // park T tile in LDS (scalar writes; stride 65 keeps epilogue reads conflict-free)
#pragma unroll
    for (int r = 0; r < 8; ++r)
#pragma unroll
      for (int c = 0; c < 4; ++c)
        Ts[ty * 8 + r][tx * 4 + c] = acc[r][c];
    __syncthreads();

    // ---- epilogue: 2 threads per i, 4 rows each; 6-term Taylor of exp(M) ----
    {
      const int i_loc = t >> 1;           // 0..127
      const int r0 = (t & 1) * 4;         // rows r0..r0+3

      float Mi[8][8];
#pragma unroll
      for (int k = 0; k < 8; ++k)
#pragma unroll
        for (int l = 0; l < 8; ++l)
          Mi[k][l] = Tjrow[k * 8 + l] - Ts[i_loc][k * 8 + l];

      float Mp[4][8], res[4][8];
#pragma unroll
      for (int r = 0; r < 4; ++r)
#pragma unroll
        for (int c = 0; c < 8; ++c) {
          const float v = Mi[r0 + r][c];
          Mp[r][c] = v;
          res[r][c] = v + ((r0 + r) == c ? 1.0f : 0.0f);
        }

      const float invn[5] = {0.5f, 1.0f / 3.0f, 0.25f, 0.2f, 1.0f / 6.0f};
#pragma unroll
      for (int n = 0; n < 5; ++n) {
        float np[4][8];
#pragma unroll
        for (int r = 0; r < 4; ++r)
#pragma unroll
          for (int c = 0; c < 8; ++c) {
            float sum = 0.f;
#pragma unroll
            for (int k = 0; k < 8; ++k) sum += Mp[r][k] * Mi[k][c];
            np[r][c] = sum * invn[n];
          }
#pragma unroll
        for (int r = 0; r < 4; ++r)
#pragma unroll
          for (int c = 0; c < 8; ++c) {
            Mp[r][c] = np[r][c];
            res[r][c] += np[r][c];
          }
      }

      const int i = i0 + i_loc;
      float* op = out + ((size_t)(b * S + i) * S + j) * MM;
#pragma unroll
      for (int r = 0; r < 4; ++r) {
        *(float4*)(op + (r0 + r) * 8)     = make_float4(res[r][0], res[r][1], res[r][2], res[r][3]);
        *(float4*)(op + (r0 + r) * 8 + 4) = make_float4(res[r][4], res[r][5], res[r][6], res[r][7]);
      }
    }
    // next tile's d0-loop barrier orders Ts rewrite after these reads
  }
}

extern "C" void kernel_launch(void* const* d_in, const int* in_sizes, int n_in,
                              void* d_out, int out_size, void* d_ws, size_t ws_size,
                              hipStream_t stream) {
  const float* x = (const float*)d_in[0];
  const float* A = (const float*)d_in[1];
  float* out = (float*)d_out;
  const int B = in_sizes[0] / (S * D);   // 4
  pt_kernel<<<dim3(B * S), dim3(256), 0, stream>>>(x, A, out, B);
}

// Round 2
// 866.261 us; speedup vs baseline: 1.5864x; 1.5864x over previous
//
#include <hip/hip_runtime.h>

// out[b,i,j,:,:] = exp6(Tjrow - T_i), T[i,m] = sum_d x[b,i,d]*A[b,j,d,m], K=8 (m=64)
// Block = (b, j, ipass): 128 i's. 4 waves; wave computes 32i x 64m via
// mfma_f32_16x16x32_bf16 (2 i-tiles x 4 m-tiles). B-operand fragments staged
// lane-linear in LDS; A-operand (X) loaded direct from global (L2-resident).
// Epilogue: 2 threads/i Taylor chain in regs; results staged in LDS so the
// final store writes full 64B lines per instruction (kills RMW write traffic).

typedef short short8 __attribute__((ext_vector_type(8)));
typedef float f32x4 __attribute__((ext_vector_type(4)));

constexpr int S = 512, D = 512, MM = 64;
constexpr int TILE_I = 128;
constexpr int TS_STRIDE = 65;   // Taylor phase (conflict-free b32 reads)
constexpr int RES_STRIDE = 68;  // write-out phase (16B-aligned rows)

// pack two f32 -> two bf16 (round-half-up) in one v_perm
__device__ inline unsigned pack2(float lo, float hi) {
  unsigned a = __float_as_uint(lo) + 0x8000u;
  unsigned b = __float_as_uint(hi) + 0x8000u;
  return __builtin_amdgcn_perm(b, a, 0x07060302);  // [a.b2,a.b3,b.b2,b.b3]
}

__global__ __launch_bounds__(256, 3)
void pt_kernel(const float* __restrict__ x, const float* __restrict__ A,
               float* __restrict__ out) {
  const int bid = blockIdx.x;
  const int b = bid >> 11;
  const int j = (bid >> 2) & (S - 1);
  const int i0 = (bid & 3) * TILE_I;
  const int t = threadIdx.x;
  const int w = t >> 6;
  const int L = t & 63;
  const int quad = L >> 4;
  const int l15 = L & 15;

  __shared__ short8 Bf[8 * 64];                   // 8 KB  (kk*4+mt)*64+L, lane-linear
  __shared__ float TsRes[TILE_I * RES_STRIDE];    // 34.8 KB union: Ts then Res
  __shared__ float Tjrow[MM];
  __shared__ float red[4][MM];

  const float* xb = x + (size_t)b * S * D;
  const float* Ab = A + (size_t)(b * S + j) * (size_t)(D * MM);

  // ---- Tjrow[m] = sum_d x[b,j,d]*A[b,j,d,m] (fp32; warms L2 with A[b,j]) ----
  {
    const int m = t & 63;
    const int part = t >> 6;
    const float* xj = xb + (size_t)j * D;
    const int dbeg = part * (D / 4);
    float acc = 0.f;
    for (int dd = 0; dd < D / 4; ++dd)
      acc += xj[dbeg + dd] * Ab[(size_t)(dbeg + dd) * MM + m];
    red[part][m] = acc;
  }
  __syncthreads();
  if (t < MM) Tjrow[t] = red[0][t] + red[1][t] + red[2][t] + red[3][t];
  // visibility: barriers inside the k-loop below precede any Tjrow read

  f32x4 acc[2][4];
#pragma unroll
  for (int it = 0; it < 2; ++it)
#pragma unroll
    for (int mt = 0; mt < 4; ++mt) acc[it][mt] = (f32x4){0.f, 0.f, 0.f, 0.f};

  const int mcol = w * 16 + l15;
  const float* xrow0 = xb + (size_t)(i0 + w * 32 + l15) * D;  // it=0 row
  const float* xrow1 = xrow0 + (size_t)16 * D;                // it=1 row

  for (int d0 = 0; d0 < D; d0 += 64) {
    __syncthreads();  // previous chunk's Bf reads complete
    // ---- stage B fragments: wave w owns m-tile w, kk = 0,1 ----
#pragma unroll
    for (int kk = 0; kk < 2; ++kk) {
      const float* ap = Ab + (size_t)(d0 + kk * 32 + quad * 8) * MM + mcol;
      const float e0 = ap[0 * MM], e1 = ap[1 * MM], e2 = ap[2 * MM], e3 = ap[3 * MM];
      const float e4 = ap[4 * MM], e5 = ap[5 * MM], e6 = ap[6 * MM], e7 = ap[7 * MM];
      union { unsigned u[4]; short8 s; } bf;
      bf.u[0] = pack2(e0, e1); bf.u[1] = pack2(e2, e3);
      bf.u[2] = pack2(e4, e5); bf.u[3] = pack2(e6, e7);
      Bf[(kk * 4 + w) * 64 + L] = bf.s;   // ds_write_b128, lane-linear
    }
    __syncthreads();
    // ---- compute: 2 kk sub-chunks x 2 i-tiles x 4 m-tiles ----
#pragma unroll
    for (int kk = 0; kk < 2; ++kk) {
      short8 bfr[4];
#pragma unroll
      for (int mt = 0; mt < 4; ++mt) bfr[mt] = Bf[(kk * 4 + mt) * 64 + L];
#pragma unroll
      for (int it = 0; it < 2; ++it) {
        const float* xp = (it ? xrow1 : xrow0) + d0 + kk * 32 + quad * 8;
        const float4 v0 = *(const float4*)xp;
        const float4 v1 = *(const float4*)(xp + 4);
        union { unsigned u[4]; short8 s; } af;
        af.u[0] = pack2(v0.x, v0.y); af.u[1] = pack2(v0.z, v0.w);
        af.u[2] = pack2(v1.x, v1.y); af.u[3] = pack2(v1.z, v1.w);
#pragma unroll
        for (int mt = 0; mt < 4; ++mt)
          acc[it][mt] = __builtin_amdgcn_mfma_f32_16x16x32_bf16(af.s, bfr[mt], acc[it][mt], 0, 0, 0);
      }
    }
  }

  // ---- park T in LDS: C/D layout col=lane&15, row=quad*4+reg ----
#pragma unroll
  for (int it = 0; it < 2; ++it)
#pragma unroll
    for (int mt = 0; mt < 4; ++mt)
#pragma unroll
      for (int r = 0; r < 4; ++r)
        TsRes[(w * 32 + it * 16 + quad * 4 + r) * TS_STRIDE + mt * 16 + l15] = acc[it][mt][r];
  __syncthreads();

  // ---- Taylor: 2 threads per i, 4 rows each ----
  {
    const int i_loc = t >> 1;
    const int r0 = (t & 1) * 4;

    float Mi[8][8];
#pragma unroll
    for (int k = 0; k < 8; ++k)
#pragma unroll
      for (int l = 0; l < 8; ++l)
        Mi[k][l] = Tjrow[k * 8 + l] - TsRes[i_loc * TS_STRIDE + k * 8 + l];
    __syncthreads();  // all Ts reads done; TsRes becomes Res

    float Mp[4][8], res[4][8];
#pragma unroll
    for (int r = 0; r < 4; ++r)
#pragma unroll
      for (int c = 0; c < 8; ++c) {
        const float v = Mi[r0 + r][c];
        Mp[r][c] = v;
        res[r][c] = v + ((r0 + r) == c ? 1.0f : 0.0f);
      }

    const float invn[5] = {0.5f, 1.0f / 3.0f, 0.25f, 0.2f, 1.0f / 6.0f};
#pragma unroll
    for (int n = 0; n < 5; ++n) {
      float np[4][8];
#pragma unroll
      for (int r = 0; r < 4; ++r)
#pragma unroll
        for (int c = 0; c < 8; ++c) {
          float sum = 0.f;
#pragma unroll
          for (int k = 0; k < 8; ++k) sum += Mp[r][k] * Mi[k][c];
          np[r][c] = sum * invn[n];
        }
#pragma unroll
      for (int r = 0; r < 4; ++r)
#pragma unroll
        for (int c = 0; c < 8; ++c) {
          Mp[r][c] = np[r][c];
          res[r][c] += np[r][c];
        }
    }

    // stage result rows in LDS (stride 68 keeps the read pass 2-way-free)
#pragma unroll
    for (int r = 0; r < 4; ++r) {
      *(float4*)&TsRes[i_loc * RES_STRIDE + (r0 + r) * 8] =
          make_float4(res[r][0], res[r][1], res[r][2], res[r][3]);
      *(float4*)&TsRes[i_loc * RES_STRIDE + (r0 + r) * 8 + 4] =
          make_float4(res[r][4], res[r][5], res[r][6], res[r][7]);
    }
  }
  __syncthreads();

  // ---- store: 16 consecutive lanes cover one 256-B (i,j) island ----
  {
    const int part = t & 15;
    const int il0 = t >> 4;  // 0..15
#pragma unroll
    for (int step = 0; step < 8; ++step) {
      const int i_loc = il0 + step * 16;
      const int i = i0 + i_loc;
      const float4 v = *(const float4*)&TsRes[i_loc * RES_STRIDE + part * 4];
      *(float4*)(out + (((size_t)(b * S + i)) * S + j) * MM + part * 4) = v;
    }
  }
}

extern "C" void kernel_launch(void* const* d_in, const int* in_sizes, int n_in,
                              void* d_out, int out_size, void* d_ws, size_t ws_size,
                              hipStream_t stream) {
  const float* x = (const float*)d_in[0];
  const float* A = (const float*)d_in[1];
  float* out = (float*)d_out;
  const int B = in_sizes[0] / (S * D);  // 4
  pt_kernel<<<dim3(B * S * 4), dim3(256), 0, stream>>>(x, A, out);
}